// Round 5
// baseline (258.811 us; speedup 1.0000x reference)
//
#include <hip/hip_runtime.h>

// Problem constants (B,C,H,W = 32,64,128,128)
static constexpr int Cc  = 64;
static constexpr int HWc = 16384;   // 128*128
static constexpr int Bc  = 32;
static constexpr int PXB = 1024;    // pixels per block
static constexpr int PH  = 64;      // pixels per phase
static constexpr int NPH = PXB / PH;  // 16 phases

// ---------------------------------------------------------------------------
// Identity (verified): sigmoid(d)+sigmoid(-d)=1 makes A[b] = -0.5*theta, so
// out[b,n,:] = W_lin @ relu(-0.5*theta @ x[b,:,n]) + b_lin.
// Round 7 = Round 6 structure with two correctness fixes (r4 post-mortem):
//   FIX1: weight staging wrote only 8 of every 16 f16 elements per segment
//         (one uint4 instead of two) -> half of M1l/Wl rows were garbage.
//   FIX2: frag extraction read pixel [lq] from the shared 64-px phase buffer;
//         wave wv's pixels are [wv*16+lq]. All waves computed pixels 0..15.
// Structure (unchanged, the thing under test): counted-vmcnt pipeline.
//   per phase: (a) issue 16 gload_lds (width 4, 1/channel-row) for the NEXT
//   64-px tile into the other xbuf -> (b) compute current tile ->
//   (w) asm s_waitcnt vmcnt(4): 4 newest vmem ops are this wave's stores;
//   vmcnt retires IN ORDER, so <=4 outstanding proves all 16 gloads landed ->
//   (s) raw s_barrier (no vmcnt-0 drain; stores cross the barrier, never
//   waited). Loads stay in flight through the whole compute phase.
//   Cross-wave safety: each wave confirms its own 16 staged rows at (w)
//   before the barrier -> after barrier the whole next tile is valid.
// mfma_f32_16x16x32_f16 layouts (HW-verified):
//   A[m=lane&15][k=quad*8+j]  B[col=lane&15][k=quad*8+j]  D[row=quad*4+r][col=lane&15]
// GEMM1 (swapped): D1 = M1 @ x   -> lane holds P[n][i=4quad+r(+16it)]
// GEMM2 (swapped): D2 = W  @ P^T -> lane holds out[n][c=4quad+r(+16ct)] -> float4 stores
// LDS pads: xbuf rows 65 dw (gload_lds width-4 fills the 64-dw interior, one
//   instr per row -> pad survives the linear-dest rule; frag b32 reads:
//   bank = c0*65+wv*16+lq mod 32, 520 % 32 = 8 -> exactly 2-way = free);
//   M1l/Wl/p2 stride 72 f16 (144B, 16B-aligned b128 reads, ~2-way).
// LDS 60928 B -> 2 blocks/CU; grid 512 = exactly 2/CU, zero tail.
// ---------------------------------------------------------------------------

typedef _Float16 v8h __attribute__((ext_vector_type(8)));
typedef float    v4f __attribute__((ext_vector_type(4)));

union FragU { uint32_t u[4]; v8h h; };

__device__ inline uint32_t packf2(float lo, float hi) {
  union { _Float16 h[2]; uint32_t u; } r;
  r.h[0] = (_Float16)lo; r.h[1] = (_Float16)hi;
  return r.u;
}

__device__ inline v4f mfma16(v8h a, v8h b, v4f c) {
  return __builtin_amdgcn_mfma_f32_16x16x32_f16(a, b, c, 0, 0, 0);
}

// width-4 global->LDS: lane i reads 4B at its own gptr, HW writes ldsbase+i*4.
__device__ inline void gload_lds4(const float* g, float* l) {
  __builtin_amdgcn_global_load_lds(
      (const __attribute__((address_space(1))) void*)g,
      (__attribute__((address_space(3))) void*)l, 4, 0, 0);
}

// Prep: f16 weights. M1h = -0.5*theta (row-major [i][c]); Wh = W_lin ([c][i]).
__global__ void prep_weights(const float* __restrict__ theta,
                             const float* __restrict__ Wlin,
                             _Float16* __restrict__ M1h,
                             _Float16* __restrict__ Wh) {
  int t = blockIdx.x * 256 + threadIdx.x;
  if (t < Cc * Cc) {
    M1h[t] = (_Float16)(-0.5f * theta[t]);
    Wh[t]  = (_Float16)(Wlin[t]);
  }
}

__global__ __launch_bounds__(256) void fused_mfma(
    const float* __restrict__ x,      // [B, C, HW]
    const _Float16* __restrict__ M1h, // [64][64]
    const _Float16* __restrict__ Wh,  // [64][64]
    const float* __restrict__ blin,   // [64]
    float* __restrict__ out)          // [B, HW, C]
{
  __shared__ __align__(16) float    xbuf[2][64][65];  // 33280 B, dbuf x tile (f32)
  __shared__ __align__(16) _Float16 M1l[64][72];      //  9216 B
  __shared__ __align__(16) _Float16 Wl [64][72];      //  9216 B
  __shared__ __align__(16) _Float16 p2 [4][16][72];   //  9216 B (per-wave)

  const int tid  = threadIdx.x;
  const int wv   = tid >> 6;
  const int l    = tid & 63;
  const int lq   = tid & 15;
  const int quad = l >> 4;
  const int pxw  = wv * 16 + lq;    // FIX2: this wave's pixel within the phase

  const int b   = blockIdx.x >> 4;          // 16 blocks per batch
  const int px0 = (blockIdx.x & 15) * PXB;
  const float* xb = x + (size_t)b * Cc * HWc;

  // ---- stage weights into LDS (FIX1: two uint4 per 16-element segment)
  {
    const int r = tid >> 2, seg = (tid & 3) * 16;
    const uint4 m0 = *(const uint4*)(M1h + r * 64 + seg);
    const uint4 m1 = *(const uint4*)(M1h + r * 64 + seg + 8);
    const uint4 w0 = *(const uint4*)(Wh  + r * 64 + seg);
    const uint4 w1 = *(const uint4*)(Wh  + r * 64 + seg + 8);
    *(uint4*)&M1l[r][seg]     = m0;
    *(uint4*)&M1l[r][seg + 8] = m1;
    *(uint4*)&Wl[r][seg]      = w0;
    *(uint4*)&Wl[r][seg + 8]  = w1;
  }
  v4f bias4[4];
#pragma unroll
  for (int ct = 0; ct < 4; ++ct)
    bias4[ct] = *(const v4f*)(blin + ct * 16 + quad * 4);

  // ---- prologue: stage phase 0 (wave wv stages rows [16wv,16wv+16))
#pragma unroll
  for (int i = 0; i < 16; ++i) {
    const int c = wv * 16 + i;
    gload_lds4(xb + (size_t)c * HWc + px0 + l, &xbuf[0][c][0]);
  }

  __syncthreads();   // drains prologue gloads + weight staging; the only full sync

  for (int t = 0; t < NPH; ++t) {
    // ---- (a) issue next phase's staging FIRST; stays in flight through (b)
    if (t < NPH - 1) {
      const int pb = px0 + (t + 1) * PH;
      float* dst = &xbuf[(t + 1) & 1][0][0];
#pragma unroll
      for (int i = 0; i < 16; ++i) {
        const int c = wv * 16 + i;
        gload_lds4(xb + (size_t)c * HWc + pb + l, dst + c * 65);
      }
      __builtin_amdgcn_sched_barrier(0);   // pin issue-early
    }

    // ---- (b) compute phase t from xbuf[t&1] (valid since barrier of t-1)
    const int kb = t & 1;
    FragU xf[2];
#pragma unroll
    for (int kt = 0; kt < 2; ++kt)
#pragma unroll
      for (int r = 0; r < 4; ++r) {
        const int c0 = kt * 32 + quad * 8 + 2 * r;
        xf[kt].u[r] = packf2(xbuf[kb][c0][pxw], xbuf[kb][c0 + 1][pxw]);  // RTE f16
      }

    // GEMM1: D1[i][n] = M1 @ x ; relu+pack -> p2[n][i] (b64 writes)
#pragma unroll
    for (int it = 0; it < 4; ++it) {
      v4f a = {0.f, 0.f, 0.f, 0.f};
#pragma unroll
      for (int kt = 0; kt < 2; ++kt)
        a = mfma16(*(const v8h*)&M1l[it * 16 + lq][kt * 32 + quad * 8],
                   xf[kt].h, a);
      uint2 w;
      w.x = packf2(fmaxf(a[0], 0.f), fmaxf(a[1], 0.f));
      w.y = packf2(fmaxf(a[2], 0.f), fmaxf(a[3], 0.f));
      *(uint2*)&p2[wv][lq][it * 16 + quad * 4] = w;
    }

    // P A-frags (in-wave DS ordering; p2 per-wave -> no barrier needed)
    FragU pr[2];
#pragma unroll
    for (int kt = 0; kt < 2; ++kt)
      pr[kt].h = *(const v8h*)&p2[wv][lq][kt * 32 + quad * 8];

    // GEMM2: D2[c][n] = W @ P^T -> out[n][c], 4 coalesced float4 stores
    float* orow = out + ((size_t)b * HWc + px0 + t * PH + pxw) * Cc + quad * 4;
#pragma unroll
    for (int ct = 0; ct < 4; ++ct) {
      v4f a = bias4[ct];
#pragma unroll
      for (int kt = 0; kt < 2; ++kt)
        a = mfma16(*(const v8h*)&Wl[ct * 16 + lq][kt * 32 + quad * 8],
                   pr[kt].h, a);
      *(v4f*)(orow + ct * 16) = a;
    }

    // ---- (w)+(s): counted wait (own gloads done; 4 newest = own stores,
    //      never waited) then RAW barrier -> next phase's tile globally valid.
    if (t < NPH - 1) {
      asm volatile("s_waitcnt vmcnt(4)" ::: "memory");
      __builtin_amdgcn_sched_barrier(0);
      __builtin_amdgcn_s_barrier();
      __builtin_amdgcn_sched_barrier(0);
    }
  }
}

extern "C" void kernel_launch(void* const* d_in, const int* in_sizes, int n_in,
                              void* d_out, int out_size, void* d_ws, size_t ws_size,
                              hipStream_t stream) {
  const float* x     = (const float*)d_in[0];
  const float* theta = (const float*)d_in[1];
  const float* W_lin = (const float*)d_in[2];
  const float* b_lin = (const float*)d_in[3];
  float* out = (float*)d_out;

  _Float16* M1h = (_Float16*)d_ws;
  _Float16* Wh  = M1h + Cc * Cc;

  prep_weights<<<(Cc * Cc + 255) / 256, 256, 0, stream>>>(theta, W_lin, M1h, Wh);

  const int nblocks = Bc * HWc / PXB;   // 512 blocks = exactly 2/CU, zero tail
  fused_mfma<<<nblocks, 256, 0, stream>>>(x, M1h, Wh, b_lin, out);
}

// Round 6
// 253.968 us; speedup vs baseline: 1.0191x; 1.0191x over previous
//
#include <hip/hip_runtime.h>

// Problem constants (B,C,H,W = 32,64,128,128)
static constexpr int Cc  = 64;
static constexpr int HWc = 16384;   // 128*128
static constexpr int Bc  = 32;
static constexpr int PXB = 1024;    // pixels per block
static constexpr int PH  = 64;      // pixels per phase
static constexpr int NPH = PXB / PH;  // 16 phases

// ---------------------------------------------------------------------------
// Identity (verified): sigmoid(d)+sigmoid(-d)=1 makes A[b] = -0.5*theta, so
// out[b,n,:] = W_lin @ relu(-0.5*theta @ x[b,:,n]) + b_lin.
// Round 8 = r5's (correct, measured) counted-vmcnt pipeline + ONE change:
//   COALESCED STORE EPILOGUE. r0-r5 all stored out[n][c] with lane=n at
//   256B lane stride: each global_store_dwordx4 touches 64 distinct 64B
//   lines with 16B partial writes = 64 transactions/instr, 4x line-touch
//   inflation in L2 (~4096 transaction-cycles per block-phase, ~55% of r5's
//   14K-cy phase). Fix: GEMM2 -> per-wave LDS ot[16][68] f32 (union with p2;
//   temporally disjoint, same-wave DS ordering -> no barrier), re-read so
//   lane l holds out-linear dword 4l -> 4 contiguous 1KB stores per
//   wave-phase (16 complete lines each).
// Pipeline (unchanged from r5): per phase (a) issue 16 gload_lds width-4
//   for next 64-px tile -> (b) compute current -> (w) s_waitcnt vmcnt(4)
//   (4 newest = own coalesced stores, never waited; in-order retirement
//   proves gloads landed) -> (s) raw s_barrier. No vmcnt-0 drain in loop.
// mfma_f32_16x16x32_f16 layouts (HW-verified):
//   A[m=lane&15][k=quad*8+j]  B[col=lane&15][k=quad*8+j]  D[row=quad*4+r][col=lane&15]
// GEMM1 (swapped): D1 = M1 @ x   -> lane holds P[n][i=4quad+r(+16it)]
// GEMM2 (swapped): D2 = W  @ P^T -> lane holds out[n][c=4quad+r(+16ct)]
// LDS: xbuf rows 65 dw (pad survives gload_lds linear-dest rule: one instr
//   per row; frag b32 reads 2-way = free); M1l/Wl stride 72 f16; scr union
//   {p2[16][72] f16, ot[16][68] f32} per wave. ot write/read ~8-way on 8
//   b128 ops/wave-phase (~100cy) -- cheap vs ~4000cy TA scatter savings.
// LDS total 69120 B -> 2 blocks/CU; grid 512 = exactly 2/CU, zero tail.
// ---------------------------------------------------------------------------

typedef _Float16 v8h __attribute__((ext_vector_type(8)));
typedef float    v4f __attribute__((ext_vector_type(4)));

union FragU { uint32_t u[4]; v8h h; };
union Scr {
  _Float16 p2[16][72];   // 2304 B: P tile [n][i], GEMM1 out / GEMM2 A-in
  float    ot[16][68];   // 4352 B: out tile [n][c], GEMM2 out / store-stage
};

__device__ inline uint32_t packf2(float lo, float hi) {
  union { _Float16 h[2]; uint32_t u; } r;
  r.h[0] = (_Float16)lo; r.h[1] = (_Float16)hi;
  return r.u;
}

__device__ inline v4f mfma16(v8h a, v8h b, v4f c) {
  return __builtin_amdgcn_mfma_f32_16x16x32_f16(a, b, c, 0, 0, 0);
}

// width-4 global->LDS: lane i reads 4B at its own gptr, HW writes ldsbase+i*4.
__device__ inline void gload_lds4(const float* g, float* l) {
  __builtin_amdgcn_global_load_lds(
      (const __attribute__((address_space(1))) void*)g,
      (__attribute__((address_space(3))) void*)l, 4, 0, 0);
}

// Prep: f16 weights. M1h = -0.5*theta (row-major [i][c]); Wh = W_lin ([c][i]).
__global__ void prep_weights(const float* __restrict__ theta,
                             const float* __restrict__ Wlin,
                             _Float16* __restrict__ M1h,
                             _Float16* __restrict__ Wh) {
  int t = blockIdx.x * 256 + threadIdx.x;
  if (t < Cc * Cc) {
    M1h[t] = (_Float16)(-0.5f * theta[t]);
    Wh[t]  = (_Float16)(Wlin[t]);
  }
}

__global__ __launch_bounds__(256) void fused_mfma(
    const float* __restrict__ x,      // [B, C, HW]
    const _Float16* __restrict__ M1h, // [64][64]
    const _Float16* __restrict__ Wh,  // [64][64]
    const float* __restrict__ blin,   // [64]
    float* __restrict__ out)          // [B, HW, C]
{
  __shared__ __align__(16) float    xbuf[2][64][65];  // 33280 B, dbuf x tile (f32)
  __shared__ __align__(16) _Float16 M1l[64][72];      //  9216 B
  __shared__ __align__(16) _Float16 Wl [64][72];      //  9216 B
  __shared__ __align__(16) Scr      scr[4];           // 17408 B (per-wave)

  const int tid  = threadIdx.x;
  const int wv   = tid >> 6;
  const int l    = tid & 63;
  const int lq   = tid & 15;
  const int quad = l >> 4;
  const int pxw  = wv * 16 + lq;    // this wave's pixel within the phase

  const int b   = blockIdx.x >> 4;          // 16 blocks per batch
  const int px0 = (blockIdx.x & 15) * PXB;
  const float* xb = x + (size_t)b * Cc * HWc;

  // ---- stage weights into LDS (two uint4 per 16-element segment)
  {
    const int r = tid >> 2, seg = (tid & 3) * 16;
    const uint4 m0 = *(const uint4*)(M1h + r * 64 + seg);
    const uint4 m1 = *(const uint4*)(M1h + r * 64 + seg + 8);
    const uint4 w0 = *(const uint4*)(Wh  + r * 64 + seg);
    const uint4 w1 = *(const uint4*)(Wh  + r * 64 + seg + 8);
    *(uint4*)&M1l[r][seg]     = m0;
    *(uint4*)&M1l[r][seg + 8] = m1;
    *(uint4*)&Wl[r][seg]      = w0;
    *(uint4*)&Wl[r][seg + 8]  = w1;
  }
  v4f bias4[4];
#pragma unroll
  for (int ct = 0; ct < 4; ++ct)
    bias4[ct] = *(const v4f*)(blin + ct * 16 + quad * 4);

  // ---- prologue: stage phase 0 (wave wv stages rows [16wv,16wv+16))
#pragma unroll
  for (int i = 0; i < 16; ++i) {
    const int c = wv * 16 + i;
    gload_lds4(xb + (size_t)c * HWc + px0 + l, &xbuf[0][c][0]);
  }

  __syncthreads();   // drains prologue gloads + weight staging; the only full sync

  for (int t = 0; t < NPH; ++t) {
    // ---- (a) issue next phase's staging FIRST; stays in flight through (b)
    if (t < NPH - 1) {
      const int pb = px0 + (t + 1) * PH;
      float* dst = &xbuf[(t + 1) & 1][0][0];
#pragma unroll
      for (int i = 0; i < 16; ++i) {
        const int c = wv * 16 + i;
        gload_lds4(xb + (size_t)c * HWc + pb + l, dst + c * 65);
      }
      __builtin_amdgcn_sched_barrier(0);   // pin issue-early
    }

    // ---- (b) compute phase t from xbuf[t&1] (valid since barrier of t-1)
    const int kb = t & 1;
    FragU xf[2];
#pragma unroll
    for (int kt = 0; kt < 2; ++kt)
#pragma unroll
      for (int r = 0; r < 4; ++r) {
        const int c0 = kt * 32 + quad * 8 + 2 * r;
        xf[kt].u[r] = packf2(xbuf[kb][c0][pxw], xbuf[kb][c0 + 1][pxw]);  // RTE f16
      }

    // GEMM1: D1[i][n] = M1 @ x ; relu+pack -> p2[n][i] (b64 writes)
#pragma unroll
    for (int it = 0; it < 4; ++it) {
      v4f a = {0.f, 0.f, 0.f, 0.f};
#pragma unroll
      for (int kt = 0; kt < 2; ++kt)
        a = mfma16(*(const v8h*)&M1l[it * 16 + lq][kt * 32 + quad * 8],
                   xf[kt].h, a);
      uint2 w;
      w.x = packf2(fmaxf(a[0], 0.f), fmaxf(a[1], 0.f));
      w.y = packf2(fmaxf(a[2], 0.f), fmaxf(a[3], 0.f));
      *(uint2*)&scr[wv].p2[lq][it * 16 + quad * 4] = w;
    }

    // P A-frags: read BEFORE any ot write (same-wave DS ordering; p2/ot alias)
    FragU pr[2];
#pragma unroll
    for (int kt = 0; kt < 2; ++kt)
      pr[kt].h = *(const v8h*)&scr[wv].p2[lq][kt * 32 + quad * 8];

    // GEMM2: D2[c][n] = W @ P^T -> lane holds out[pxw][ct*16+quad*4 .. +3]
    // Stage into per-wave ot (b128 LDS writes), NOT scattered global stores.
#pragma unroll
    for (int ct = 0; ct < 4; ++ct) {
      v4f a = bias4[ct];
#pragma unroll
      for (int kt = 0; kt < 2; ++kt)
        a = mfma16(*(const v8h*)&Wl[ct * 16 + lq][kt * 32 + quad * 8],
                   pr[kt].h, a);
      *(v4f*)&scr[wv].ot[lq][ct * 16 + quad * 4] = a;
    }

    // ---- coalesced store epilogue: wave's 16 px x 256B = 4KB contiguous.
    // Lane l, instr i: reads ot[(l>>4)+4i][(l&15)*4] == out-linear dword
    // i*256 + 4l  ->  4 x 1KB fully-coalesced global_store_dwordx4.
    {
      float* obase = out + ((size_t)b * HWc + px0 + t * PH + wv * 16) * Cc;
#pragma unroll
      for (int i = 0; i < 4; ++i) {
        const v4f v = *(const v4f*)&scr[wv].ot[(l >> 4) + 4 * i][(l & 15) * 4];
        *(v4f*)(obase + i * 256 + l * 4) = v;
      }
    }

    // ---- (w)+(s): counted wait (own gloads done; 4 newest = own coalesced
    //      stores, never waited) then RAW barrier -> next tile globally valid.
    if (t < NPH - 1) {
      asm volatile("s_waitcnt vmcnt(4)" ::: "memory");
      __builtin_amdgcn_sched_barrier(0);
      __builtin_amdgcn_s_barrier();
      __builtin_amdgcn_sched_barrier(0);
    }
  }
}

extern "C" void kernel_launch(void* const* d_in, const int* in_sizes, int n_in,
                              void* d_out, int out_size, void* d_ws, size_t ws_size,
                              hipStream_t stream) {
  const float* x     = (const float*)d_in[0];
  const float* theta = (const float*)d_in[1];
  const float* W_lin = (const float*)d_in[2];
  const float* b_lin = (const float*)d_in[3];
  float* out = (float*)d_out;

  _Float16* M1h = (_Float16*)d_ws;
  _Float16* Wh  = M1h + Cc * Cc;

  prep_weights<<<(Cc * Cc + 255) / 256, 256, 0, stream>>>(theta, W_lin, M1h, Wh);

  const int nblocks = Bc * HWc / PXB;   // 512 blocks = exactly 2/CU, zero tail
  fused_mfma<<<nblocks, 256, 0, stream>>>(x, M1h, Wh, b_lin, out);
}